// Round 15
// baseline (448.380 us; speedup 1.0000x reference)
//
#include <hip/hip_runtime.h>
#include <math.h>

#define L_SEQ 4096
#define DMODEL 512
#define DIN    1024
#define DI     1024
#define DS     16
#define DC     4
#define DTR    32
#define NCHK   512
#define CL     8
#define NPAIR  (DI * DS)
#define NG     32
#define GS     16
#define SLAB   (L_SEQ * 64)

typedef __bf16 bf16x8 __attribute__((ext_vector_type(8)));
typedef __bf16 bf16x4 __attribute__((ext_vector_type(4)));
typedef float floatx4 __attribute__((ext_vector_type(4)));

#define RLN2 1.44269504f
#define LN2  0.69314718f

__device__ __forceinline__ float softplus_fast(float x) {
    if (x > 20.f) return x;
    float e = __builtin_amdgcn_exp2f(x * RLN2);
    return LN2 * __builtin_amdgcn_logf(1.f + e);
}

__device__ __forceinline__ void gl2lds16(const __bf16* g, __bf16* l) {
    __builtin_amdgcn_global_load_lds(
        (const __attribute__((address_space(1))) void*)g,
        (__attribute__((address_space(3))) void*)l, 16, 0, 0);
}

// ---------------------------------------------------------------------------
// bf16 MFMA GEMM. ACT: 0 none, 1 relu, 2 tanh, 3 softplus.
// ---------------------------------------------------------------------------
template <int BN, int ACT, bool BIAS, bool ADDDEST, bool OUTBF, int KS>
__global__ __launch_bounds__(256) void gemm_mfma(
    const __bf16* __restrict__ A, int lda,
    const __bf16* __restrict__ W, int ldw,
    const float* __restrict__ bias,
    float* __restrict__ C, __bf16* __restrict__ Cb, int ldc, int K)
{
    __shared__ __align__(16) __bf16 sA[128 * 32];
    __shared__ __align__(16) __bf16 sB[BN * 32];
    const int tid = threadIdx.x;
    const int wid = tid >> 6, lane = tid & 63;
    const int m0 = blockIdx.y * 128;
    int n0;
    if (KS > 1) {
        const int ksl = blockIdx.x;
        A += (size_t)ksl * K;
        W += (size_t)ksl * K;
        C += (size_t)ksl * (size_t)gridDim.y * 128 * ldc;
        n0 = 0;
    } else {
        n0 = blockIdx.x * BN;
    }

    constexpr int MR = (BN == 128) ? 4 : 2;
    constexpr int NR = 4;
    const int wrow = (BN == 128) ? (wid >> 1) * 64 : wid * 32;
    const int wcol = (BN == 128) ? (wid & 1) * 64 : 0;

    const int srowA0 = wid * 32 + (lane >> 2);
    const int scol   = (lane & 3) * 8;
    const __bf16* aSrc0 = A + (size_t)(m0 + srowA0) * lda + scol;
    const __bf16* aSrc1 = aSrc0 + 16 * (size_t)lda;
    __bf16* aDst0 = &sA[wid * 1024];
    __bf16* aDst1 = &sA[wid * 1024 + 512];

    const __bf16* bSrc0;
    const __bf16* bSrc1 = nullptr;
    __bf16* bDst0;
    __bf16* bDst1 = nullptr;
    if (BN == 128) {
        bSrc0 = W + (size_t)(n0 + wid * 32 + (lane >> 2)) * ldw + scol;
        bSrc1 = bSrc0 + 16 * (size_t)ldw;
        bDst0 = &sB[wid * 1024];
        bDst1 = &sB[wid * 1024 + 512];
    } else {
        bSrc0 = W + (size_t)(n0 + wid * 16 + (lane >> 2)) * ldw + scol;
        bDst0 = &sB[wid * 512];
    }

    floatx4 acc[MR][NR] = {};
    const int fr = lane & 15;
    const int fk = (lane >> 4) * 8;

    for (int k0 = 0; k0 < K; k0 += 32) {
        __syncthreads();
        gl2lds16(aSrc0 + k0, aDst0);
        gl2lds16(aSrc1 + k0, aDst1);
        gl2lds16(bSrc0 + k0, bDst0);
        if (BN == 128) gl2lds16(bSrc1 + k0, bDst1);
        __syncthreads();
        bf16x8 af[MR], bfv[NR];
#pragma unroll
        for (int i = 0; i < MR; ++i)
            af[i] = *(const bf16x8*)&sA[(wrow + i * 16 + fr) * 32 + fk];
#pragma unroll
        for (int j = 0; j < NR; ++j)
            bfv[j] = *(const bf16x8*)&sB[(wcol + j * 16 + fr) * 32 + fk];
#pragma unroll
        for (int i = 0; i < MR; ++i)
#pragma unroll
            for (int j = 0; j < NR; ++j)
                acc[i][j] = __builtin_amdgcn_mfma_f32_16x16x32_bf16(
                    af[i], bfv[j], acc[i][j], 0, 0, 0);
    }

#pragma unroll
    for (int i = 0; i < MR; ++i)
#pragma unroll
        for (int j = 0; j < NR; ++j) {
            const int n = n0 + wcol + j * 16 + fr;
            float bv = 0.f;
            if (BIAS) bv = bias[n];
#pragma unroll
            for (int r = 0; r < 4; ++r) {
                const int m = m0 + wrow + i * 16 + (lane >> 4) * 4 + r;
                float v = acc[i][j][r] + bv;
                if (ACT == 1) v = fmaxf(v, 0.f);
                else if (ACT == 2) v = tanhf(v);
                else if (ACT == 3) v = softplus_fast(v);
                const size_t idx = (size_t)m * ldc + n;
                if (OUTBF) {
                    Cb[idx] = (__bf16)v;
                } else {
                    if (ADDDEST) v += C[idx];
                    C[idx] = v;
                }
            }
        }
}

// ---------------------------------------------------------------------------
// weight prep: 5 f32->bf16 converts + As2 table, 1 launch
__global__ void prep_k(const float* __restrict__ s0, __bf16* __restrict__ d0, int n0,
                       const float* __restrict__ s1, __bf16* __restrict__ d1, int n1,
                       const float* __restrict__ s2, __bf16* __restrict__ d2, int n2,
                       const float* __restrict__ s3, __bf16* __restrict__ d3, int n3,
                       const float* __restrict__ s4, __bf16* __restrict__ d4, int n4,
                       const float* __restrict__ Alog, float* __restrict__ As2T, int n6)
{
    int i = blockIdx.x * 256 + threadIdx.x;
    int tot = n0 + n1 + n2 + n3 + n4;
    if (i >= tot) {
        int k = i - tot;
        if (k < n6) As2T[k] = -__expf(Alog[k]) * RLN2;
        return;
    }
    const float* s; __bf16* d; int base;
    if (i < n0) { s = s0; d = d0; base = i; }
    else if (i < n0 + n1) { s = s1; d = d1; base = i - n0; }
    else if (i < n0 + n1 + n2) { s = s2; d = d2; base = i - n0 - n1; }
    else if (i < n0 + n1 + n2 + n3) { s = s3; d = d3; base = i - n0 - n1 - n2; }
    else { s = s4; d = d4; base = i - n0 - n1 - n2 - n3; }
    float4 a = ((const float4*)s)[2 * base], b = ((const float4*)s)[2 * base + 1];
    bf16x8 v;
    v[0] = (__bf16)a.x; v[1] = (__bf16)a.y; v[2] = (__bf16)a.z; v[3] = (__bf16)a.w;
    v[4] = (__bf16)b.x; v[5] = (__bf16)b.y; v[6] = (__bf16)b.z; v[7] = (__bf16)b.w;
    *(bf16x8*)&d[8 * base] = v;
}

// W2[l][d][k] = sum_r dtw[l][d][r] * xpw[l][r][k]  (r < 32), bf16 out.
// grid (ktile=4, dtile=16, l=2), 256 threads. LDS: xpw tile 32x256 + dtw 64x32.
__global__ __launch_bounds__(256) void w2_k(
    const float* __restrict__ dtw, const float* __restrict__ xpw,
    __bf16* __restrict__ W2)
{
    const int tid = threadIdx.x;
    const int kbase = blockIdx.x * 256;
    const int dbase = blockIdx.y * 64;
    const int l = blockIdx.z;
    __shared__ float xpw_s[32][256];
    __shared__ float dtw_s[64][32];
#pragma unroll
    for (int u = 0; u < 32; ++u) {
        int e = u * 256 + tid;
        int r = e >> 8, k = e & 255;
        xpw_s[r][k] = xpw[(size_t)l * 65536 + r * 1024 + kbase + k];
    }
#pragma unroll
    for (int u = 0; u < 8; ++u) {
        int e = u * 256 + tid;
        int dd = e >> 5, r = e & 31;
        dtw_s[dd][r] = dtw[(size_t)l * 32768 + (dbase + dd) * 32 + r];
    }
    __syncthreads();
    for (int dd = 0; dd < 64; ++dd) {
        float acc = 0.f;
#pragma unroll
        for (int r = 0; r < 32; ++r)
            acc = fmaf(dtw_s[dd][r], xpw_s[r][tid], acc);
        W2[(size_t)l * 1048576 + (size_t)(dbase + dd) * 1024 + kbase + tid] = (__bf16)acc;
    }
}

__global__ void concat_bf_k(const float* __restrict__ a,
                            const float* __restrict__ b,
                            __bf16* __restrict__ o)
{
    int idx = blockIdx.x * 256 + threadIdx.x;
    int m = idx >> 7, c8 = (idx & 127) << 3;
    const float* src = (c8 < 512) ? &a[(m << 9) + c8] : &b[(m << 9) + c8 - 512];
    float4 x = ((const float4*)src)[0], y = ((const float4*)src)[1];
    bf16x8 v;
    v[0] = (__bf16)x.x; v[1] = (__bf16)x.y; v[2] = (__bf16)x.z; v[3] = (__bf16)x.w;
    v[4] = (__bf16)y.x; v[5] = (__bf16)y.y; v[6] = (__bf16)y.z; v[7] = (__bf16)y.w;
    *(bf16x8*)&o[idx << 3] = v;
}

// LayerNorm over D=512. OMODE: 0 f32, 1 bf16, 2 both.
template <int OMODE>
__global__ __launch_bounds__(128) void layernorm_k(
    const float* __restrict__ X, const float* __restrict__ w,
    const float* __restrict__ b, float* __restrict__ Yf, __bf16* __restrict__ Yb)
{
    const int r = blockIdx.x, tid = threadIdx.x;
    const size_t base = ((size_t)r << 9) + (tid << 2);
    const float4 v = *(const float4*)&X[base];
    float s = v.x + v.y + v.z + v.w;
#pragma unroll
    for (int o = 32; o; o >>= 1) s += __shfl_down(s, o, 64);
    __shared__ float red[2];
    if ((tid & 63) == 0) red[tid >> 6] = s;
    __syncthreads();
    const float mean = (red[0] + red[1]) * (1.f / 512.f);
    float dx = v.x - mean, dy = v.y - mean, dz = v.z - mean, dw = v.w - mean;
    float q = dx * dx + dy * dy + dz * dz + dw * dw;
#pragma unroll
    for (int o = 32; o; o >>= 1) q += __shfl_down(q, o, 64);
    __shared__ float red2[2];
    if ((tid & 63) == 0) red2[tid >> 6] = q;
    __syncthreads();
    const float rs = rsqrtf((red2[0] + red2[1]) * (1.f / 512.f) + 1e-5f);
    const float4 wv = *(const float4*)&w[tid << 2];
    const float4 bv = *(const float4*)&b[tid << 2];
    float o0 = dx * rs * wv.x + bv.x;
    float o1 = dy * rs * wv.y + bv.y;
    float o2 = dz * rs * wv.z + bv.z;
    float o3 = dw * rs * wv.w + bv.w;
    if (OMODE != 1) {
        float4 ov; ov.x = o0; ov.y = o1; ov.z = o2; ov.w = o3;
        *(float4*)&Yf[base] = ov;
    }
    if (OMODE != 0) {
        bf16x4 ov; ov[0] = (__bf16)o0; ov[1] = (__bf16)o1;
        ov[2] = (__bf16)o2; ov[3] = (__bf16)o3;
        *(bf16x4*)&Yb[base] = ov;
    }
}

// depthwise causal conv (DC=4) + SiLU. 4 channels x 1 timestep per thread.
__global__ void conv_silu_k(const __bf16* __restrict__ XZb,
                            const float* __restrict__ cw,
                            const float* __restrict__ cb,
                            __bf16* __restrict__ XCb)
{
    int i = blockIdx.x * 256 + threadIdx.x;
    int t = i >> 8, d4 = (i & 255) << 2;
    float wt[4][4];
#pragma unroll
    for (int d = 0; d < 4; ++d) {
        float4 w = *(const float4*)&cw[(d4 + d) << 2];
        wt[d][0] = w.x; wt[d][1] = w.y; wt[d][2] = w.z; wt[d][3] = w.w;
    }
    float4 c = *(const float4*)&cb[d4];
    float a0 = c.x, a1 = c.y, a2 = c.z, a3 = c.w;
#pragma unroll
    for (int k = 0; k < 4; ++k) {
        int ts = t + k - 3;
        if (ts >= 0) {
            bf16x4 x = *(const bf16x4*)&XZb[((size_t)ts << 11) + d4];
            a0 = fmaf((float)x[0], wt[0][k], a0);
            a1 = fmaf((float)x[1], wt[1][k], a1);
            a2 = fmaf((float)x[2], wt[2][k], a2);
            a3 = fmaf((float)x[3], wt[3][k], a3);
        }
    }
    a0 *= 1.f / (1.f + __expf(-a0));
    a1 *= 1.f / (1.f + __expf(-a1));
    a2 *= 1.f / (1.f + __expf(-a2));
    a3 *= 1.f / (1.f + __expf(-a3));
    bf16x4 ob; ob[0] = (__bf16)a0; ob[1] = (__bf16)a1;
    ob[2] = (__bf16)a2; ob[3] = (__bf16)a3;
    *(bf16x4*)&XCb[((size_t)t << 10) + d4] = ob;
}

// ---------------------------------------------------------------------------
// scanA: lean per-chunk local scan. dt comes precomputed from dtg (GEMM).
// Emits sH and dtsum[c][d].
// ---------------------------------------------------------------------------
__global__ __launch_bounds__(256) void scanA_k(
    const __bf16* __restrict__ xc, const float* __restrict__ xdblP,
    const __bf16* __restrict__ dtg, const float* __restrict__ As2T,
    __bf16* __restrict__ dtsum, __bf16* __restrict__ sH)
{
    const int d = blockIdx.x * 256 + threadIdx.x;
    const int c = blockIdx.y;
    const int tid = threadIdx.x;
    __shared__ float Bs[CL][DS];
    if (tid < CL * DS) {
        int t = tid >> 4, s = tid & 15;
        size_t g = (size_t)(c * CL + t) * 64 + 32 + s;
        Bs[t][s] = xdblP[g] + xdblP[SLAB + g] + xdblP[2 * SLAB + g] + xdblP[3 * SLAB + g];
    }
    __syncthreads();
    float As2[DS], h[DS];
    {
        const float4* Ap4 = (const float4*)&As2T[(size_t)d * DS];
#pragma unroll
        for (int q = 0; q < 4; ++q) {
            float4 a = Ap4[q];
            As2[q * 4 + 0] = a.x; As2[q * 4 + 1] = a.y;
            As2[q * 4 + 2] = a.z; As2[q * 4 + 3] = a.w;
        }
    }
#pragma unroll
    for (int s = 0; s < DS; ++s) h[s] = 0.f;
    float sumdt = 0.f;
    for (int t = 0; t < CL; ++t) {
        size_t tg = (size_t)(c * CL + t);
        float dtv = (float)dtg[(tg << 10) + d];
        float xv  = (float)xc[(tg << 10) + d];
        float dx = dtv * xv;
        sumdt += dtv;
        float barr[16];
#pragma unroll
        for (int q = 0; q < 4; ++q) {
            float4 b = *(const float4*)&Bs[t][q * 4];
            barr[q * 4 + 0] = b.x; barr[q * 4 + 1] = b.y;
            barr[q * 4 + 2] = b.z; barr[q * 4 + 3] = b.w;
        }
#pragma unroll
        for (int s = 0; s < DS; ++s) {
            float a = exp2f(dtv * As2[s]);
            h[s] = fmaf(a, h[s], dx * barr[s]);
        }
    }
    dtsum[(size_t)c * DI + d] = (__bf16)sumdt;
    size_t base = ((size_t)c * DI + d) * DS;
    bf16x8 h0v, h1v;
#pragma unroll
    for (int s = 0; s < 8; ++s) {
        h0v[s] = (__bf16)h[s];
        h1v[s] = (__bf16)h[s + 8];
    }
    *(bf16x8*)&sH[base] = h0v; *(bf16x8*)&sH[base + 8] = h1v;
}

// ---------------------------------------------------------------------------
// Hierarchical chunk-scan. P recomputed from dtsum + As2T.
// ---------------------------------------------------------------------------
__global__ __launch_bounds__(256) void scanB1_k(
    const __bf16* __restrict__ dtsum, const __bf16* __restrict__ sH,
    const float* __restrict__ As2T,
    __bf16* __restrict__ PG, __bf16* __restrict__ HG)
{
    int p = blockIdx.x * 256 + threadIdx.x;
    int g = blockIdx.y;
    const int d = p >> 4;
    const float as2 = As2T[p];
    float rp = 1.f, rh = 0.f;
#pragma unroll
    for (int k = 0; k < GS; ++k) {
        int c = g * GS + k;
        float P = exp2f(as2 * (float)dtsum[(size_t)c * DI + d]);
        float H = (float)sH[(size_t)c * NPAIR + p];
        rh = fmaf(P, rh, H);
        rp *= P;
    }
    PG[(size_t)g * NPAIR + p] = (__bf16)rp;
    HG[(size_t)g * NPAIR + p] = (__bf16)rh;
}

__global__ __launch_bounds__(256) void scanB2_k(
    const __bf16* __restrict__ PG, const __bf16* __restrict__ HG,
    __bf16* __restrict__ Gin)
{
    int p = blockIdx.x * 256 + threadIdx.x;
    float run = 0.f;
#pragma unroll
    for (int g = 0; g < NG; ++g) {
        size_t idx = (size_t)g * NPAIR + p;
        Gin[idx] = (__bf16)run;
        run = fmaf((float)PG[idx], run, (float)HG[idx]);
    }
}

__global__ __launch_bounds__(256) void scanB3_k(
    const __bf16* __restrict__ dtsum, const __bf16* __restrict__ sH,
    const float* __restrict__ As2T,
    const __bf16* __restrict__ Gin, __bf16* __restrict__ Hin)
{
    int p = blockIdx.x * 256 + threadIdx.x;
    int g = blockIdx.y;
    const int d = p >> 4;
    const float as2 = As2T[p];
    float run = (float)Gin[(size_t)g * NPAIR + p];
#pragma unroll
    for (int k = 0; k < GS; ++k) {
        int c = g * GS + k;
        size_t idx = (size_t)c * NPAIR + p;
        Hin[idx] = (__bf16)run;
        float P = exp2f(as2 * (float)dtsum[(size_t)c * DI + d]);
        run = fmaf(P, run, (float)sH[idx]);
    }
}

__global__ __launch_bounds__(256) void scanC_k(
    const __bf16* __restrict__ xc, const float* __restrict__ xdblP,
    const __bf16* __restrict__ dtg, const float* __restrict__ As2T,
    const float* __restrict__ Dp, const __bf16* __restrict__ XZb,
    const __bf16* __restrict__ Hin, __bf16* __restrict__ yz)
{
    const int d = blockIdx.x * 256 + threadIdx.x;
    const int c = blockIdx.y;
    const int tid = threadIdx.x;
    __shared__ float Bs[CL][DS], Cs[CL][DS];
    if (tid < CL * DS) {
        int t = tid >> 4, s = tid & 15;
        size_t g = (size_t)(c * CL + t) * 64 + 32 + s;
        Bs[t][s] = xdblP[g] + xdblP[SLAB + g] + xdblP[2 * SLAB + g] + xdblP[3 * SLAB + g];
        g += 16;
        Cs[t][s] = xdblP[g] + xdblP[SLAB + g] + xdblP[2 * SLAB + g] + xdblP[3 * SLAB + g];
    }
    __syncthreads();
    float As2[DS], h[DS];
    {
        const float4* Ap4 = (const float4*)&As2T[(size_t)d * DS];
#pragma unroll
        for (int q = 0; q < 4; ++q) {
            float4 a = Ap4[q];
            As2[q * 4 + 0] = a.x; As2[q * 4 + 1] = a.y;
            As2[q * 4 + 2] = a.z; As2[q * 4 + 3] = a.w;
        }
    }
    {
        size_t base = ((size_t)c * DI + d) * DS;
        bf16x8 h0 = *(const bf16x8*)&Hin[base];
        bf16x8 h1 = *(const bf16x8*)&Hin[base + 8];
#pragma unroll
        for (int s = 0; s < 8; ++s) { h[s] = (float)h0[s]; h[s + 8] = (float)h1[s]; }
    }
    const float Dd = Dp[d];
    for (int t = 0; t < CL; ++t) {
        size_t tg = (size_t)(c * CL + t);
        const float dtv = (float)dtg[(tg << 10) + d];
        const float xv = (float)xc[(tg << 10) + d];
        const float dx = dtv * xv;
        float barr[16], carr[16];
#pragma unroll
        for (int q = 0; q < 4; ++q) {
            float4 b = *(const float4*)&Bs[t][q * 4];
            float4 cc = *(const float4*)&Cs[t][q * 4];
            barr[q * 4 + 0] = b.x; barr[q * 4 + 1] = b.y;
            barr[q * 4 + 2] = b.z; barr[q * 4 + 3] = b.w;
            carr[q * 4 + 0] = cc.x; carr[q * 4 + 1] = cc.y;
            carr[q * 4 + 2] = cc.z; carr[q * 4 + 3] = cc.w;
        }
        float y = 0.f;
#pragma unroll
        for (int s = 0; s < DS; ++s) {
            float a = exp2f(dtv * As2[s]);
            h[s] = fmaf(a, h[s], dx * barr[s]);
            y = fmaf(h[s], carr[s], y);
        }
        y = fmaf(Dd, xv, y);
        float zv = (float)XZb[(tg << 11) + 1024 + d];
        float sg = 1.f / (1.f + __expf(-zv));
        yz[(tg << 10) + d] = (__bf16)(y * (zv * sg));
    }
}

// ---------------------------------------------------------------------------
// Attention pooling tail
// ---------------------------------------------------------------------------
__global__ void score_k(const float* __restrict__ At,
                        const float* __restrict__ w2,
                        const float* __restrict__ b2,
                        float* __restrict__ sc)
{
    int t = blockIdx.x * 256 + threadIdx.x;
    const float4* a = (const float4*)(At + ((size_t)t << 7));
    const float4* w = (const float4*)w2;
    float acc = 0.f;
#pragma unroll
    for (int j = 0; j < 32; ++j) {
        float4 av = a[j], wv = w[j];
        acc += av.x * wv.x + av.y * wv.y + av.z * wv.z + av.w * wv.w;
    }
    sc[t] = acc + b2[0];
}

__global__ __launch_bounds__(256) void softmax_k(const float* __restrict__ s,
                                                 float* __restrict__ p)
{
    const int tid = threadIdx.x;
    float vals[16];
#pragma unroll
    for (int i = 0; i < 4; ++i) {
        float4 v = *(const float4*)&s[(tid << 4) + (i << 2)];
        vals[i * 4 + 0] = v.x; vals[i * 4 + 1] = v.y;
        vals[i * 4 + 2] = v.z; vals[i * 4 + 3] = v.w;
    }
    float mx = -1e30f;
#pragma unroll
    for (int i = 0; i < 16; ++i) mx = fmaxf(mx, vals[i]);
#pragma unroll
    for (int o = 32; o; o >>= 1) mx = fmaxf(mx, __shfl_xor(mx, o, 64));
    __shared__ float red[4];
    if ((tid & 63) == 0) red[tid >> 6] = mx;
    __syncthreads();
    mx = fmaxf(fmaxf(red[0], red[1]), fmaxf(red[2], red[3]));
    float sum = 0.f, e[16];
#pragma unroll
    for (int i = 0; i < 16; ++i) { e[i] = __expf(vals[i] - mx); sum += e[i]; }
#pragma unroll
    for (int o = 32; o; o >>= 1) sum += __shfl_xor(sum, o, 64);
    __syncthreads();
    if ((tid & 63) == 0) red[tid >> 6] = sum;
    __syncthreads();
    sum = red[0] + red[1] + red[2] + red[3];
    float inv = 1.f / sum;
#pragma unroll
    for (int i = 0; i < 4; ++i) {
        float4 ov;
        ov.x = e[i * 4 + 0] * inv; ov.y = e[i * 4 + 1] * inv;
        ov.z = e[i * 4 + 2] * inv; ov.w = e[i * 4 + 3] * inv;
        *(float4*)&p[(tid << 4) + (i << 2)] = ov;
    }
}

__global__ void pool_partial_k(const float* __restrict__ prob,
                               const float* __restrict__ hln,
                               float* __restrict__ part)
{
    int j = blockIdx.x * 256 + threadIdx.x;
    int c = blockIdx.y;
    float acc = 0.f;
    for (int t = c * 128; t < (c + 1) * 128; ++t)
        acc = fmaf(prob[t], hln[((size_t)t << 9) + j], acc);
    part[c * 512 + j] = acc;
}

__global__ void pool_reduce_k(const float* __restrict__ part,
                              float* __restrict__ hp)
{
    int j = blockIdx.x * 256 + threadIdx.x;
    float acc = 0.f;
    for (int c = 0; c < 32; ++c) acc += part[c * 512 + j];
    hp[j] = acc;
}

__global__ __launch_bounds__(256) void final_head_k(
    const float* __restrict__ hp, const float* __restrict__ cls_w,
    const float* __restrict__ cls_b, const int* __restrict__ label,
    float* __restrict__ out)
{
    const int w = threadIdx.x >> 6, lane = threadIdx.x & 63;
    float acc = 0.f;
    for (int k = lane; k < 512; k += 64) acc += hp[k] * cls_w[w * 512 + k];
#pragma unroll
    for (int o = 32; o; o >>= 1) acc += __shfl_down(acc, o, 64);
    __shared__ float lg[4];
    if (lane == 0) lg[w] = acc + cls_b[w];
    __syncthreads();
    if (threadIdx.x == 0) {
        float lce[4];
        for (int c = 0; c < 4; ++c) {
            float z = lg[c];
            float hz = 1.f / (1.f + expf(-z));
            float pc = fminf(fmaxf(hz, 1e-6f), 1.f - 1e-6f);
            lce[c] = logf(pc) - log1pf(-pc);
        }
        float mx = fmaxf(fmaxf(lce[0], lce[1]), fmaxf(lce[2], lce[3]));
        float se = 0.f;
        for (int c = 0; c < 4; ++c) se += expf(lce[c] - mx);
        for (int c = 0; c < 4; ++c) out[c] = lce[c];
        for (int c = 0; c < 4; ++c) out[4 + c] = expf(lce[c] - mx) / se;
        int lb = label[0];
        out[8] = -(lce[lb] - mx - logf(se));
    }
}

// ---------------------------------------------------------------------------
extern "C" void kernel_launch(void* const* d_in, const int* in_sizes, int n_in,
                              void* d_out, int out_size, void* d_ws, size_t ws_size,
                              hipStream_t stream)
{
    const float* data_s   = (const float*)d_in[0];
    const float* data_l   = (const float*)d_in[1];
    const int*   label    = (const int*)d_in[3];
    const float* fc1_w    = (const float*)d_in[4];
    const float* fc1_b    = (const float*)d_in[5];
    const float* ln_w     = (const float*)d_in[6];
    const float* ln_b     = (const float*)d_in[7];
    const float* in_proj_w= (const float*)d_in[8];
    const float* conv_w   = (const float*)d_in[9];
    const float* conv_b   = (const float*)d_in[10];
    const float* x_proj_w = (const float*)d_in[11];
    const float* dt_proj_w= (const float*)d_in[12];
    const float* dt_proj_b= (const float*)d_in[13];
    const float* A_log    = (const float*)d_in[14];
    const float* D_param  = (const float*)d_in[15];
    const float* out_proj_w=(const float*)d_in[16];
    const float* norm_w   = (const float*)d_in[17];
    const float* norm_b   = (const float*)d_in[18];
    const float* attn_w1  = (const float*)d_in[19];
    const float* attn_b1  = (const float*)d_in[20];
    const float* attn_w2  = (const float*)d_in[21];
    const float* attn_b2  = (const float*)d_in[22];
    const float* cls_w    = (const float*)d_in[23];
    const float* cls_b    = (const float*)d_in[24];
    float* out = (float*)d_out;

    // ---- f32 workspace ----
    float* ws = (float*)d_ws;
    size_t off = 0;
    float* h     = ws + off; off += (size_t)L_SEQ * DMODEL;
    float* hn    = ws + off; off += (size_t)L_SEQ * DMODEL;
    float* xdblP = ws + off; off += (size_t)4 * SLAB;
    float* As2T  = ws + off; off += (size_t)2 * DI * DS;
    float* At    = ws + off; off += (size_t)L_SEQ * 128;
    float* sc    = ws + off; off += L_SEQ;
    float* pb    = ws + off; off += L_SEQ;
    float* part  = ws + off; off += 32 * 512;
    float* hp    = ws + off; off += 512;

    // ---- bf16 workspace ----
    __bf16* bws = (__bf16*)(ws + off);
    size_t boff = 0;
    __bf16* Acatb = bws + boff; boff += (size_t)L_SEQ * DIN;
    __bf16* hnb   = bws + boff; boff += (size_t)L_SEQ * DMODEL;
    __bf16* XZb   = bws + boff; boff += (size_t)L_SEQ * 2 * DI;
    __bf16* XCb   = bws + boff; boff += (size_t)L_SEQ * DI;
    __bf16* yzb   = bws + boff; boff += (size_t)L_SEQ * DI;
    __bf16* sHb   = bws + boff; boff += (size_t)NCHK * NPAIR;
    __bf16* HinB  = bws + boff; boff += (size_t)NCHK * NPAIR;
    __bf16* dtgB  = bws + boff; boff += (size_t)L_SEQ * DI;
    __bf16* dtsumB= bws + boff; boff += (size_t)NCHK * DI;
    __bf16* PGb   = bws + boff; boff += (size_t)NG * NPAIR;
    __bf16* HGb   = bws + boff; boff += (size_t)NG * NPAIR;
    __bf16* GinB  = bws + boff; boff += (size_t)NG * NPAIR;
    __bf16* wfc1b = bws + boff; boff += (size_t)DMODEL * DIN;
    __bf16* winb  = bws + boff; boff += (size_t)2 * 2 * DI * DMODEL;
    __bf16* wxpb  = bws + boff; boff += (size_t)2 * 64 * DI;
    __bf16* woutb = bws + boff; boff += (size_t)2 * DMODEL * DI;
    __bf16* w1b   = bws + boff; boff += (size_t)128 * DMODEL;
    __bf16* W2b   = bws + boff; boff += (size_t)2 * DI * DI;
    if (ws_size < off * sizeof(float) + boff * sizeof(__bf16)) return;

    // ---- weight prep ----
    const int n0 = DMODEL * DIN / 8;
    const int n1 = 2 * 2 * DI * DMODEL / 8;
    const int n2 = 2 * 64 * DI / 8;
    const int n3 = 2 * DMODEL * DI / 8;
    const int n4 = 128 * DMODEL / 8;
    const int n6 = 2 * DI * DS;
    prep_k<<<(n0 + n1 + n2 + n3 + n4 + n6 + 255) / 256, 256, 0, stream>>>(
        fc1_w, wfc1b, n0, in_proj_w, winb, n1, x_proj_w, wxpb, n2,
        out_proj_w, woutb, n3, attn_w1, w1b, n4, A_log, As2T, n6);
    w2_k<<<dim3(4, 16, 2), 256, 0, stream>>>(dt_proj_w, x_proj_w, W2b);

    // h = relu(concat @ fc1_w.T + b)
    concat_bf_k<<<L_SEQ * DIN / 8 / 256, 256, 0, stream>>>(data_s, data_l, Acatb);
    gemm_mfma<64, 1, true, false, false, 1><<<dim3(DMODEL / 64, L_SEQ / 128), 256, 0, stream>>>(
        Acatb, DIN, wfc1b, DIN, fc1_b, h, nullptr, DMODEL, DIN);

    for (int i = 0; i < 2; ++i) {
        const __bf16* inw = winb + (size_t)i * 2 * DI * DMODEL;
        const float* cwi = conv_w + (size_t)i * DI * DC;
        const float* cbi = conv_b + (size_t)i * DI;
        const __bf16* xpw = wxpb + (size_t)i * 64 * DI;
        const __bf16* W2i = W2b + (size_t)i * DI * DI;
        const float* dtbv= dt_proj_b + (size_t)i * DI;
        const float* As2i = As2T + (size_t)i * DI * DS;
        const float* Dpi = D_param + (size_t)i * DI;
        const __bf16* owi = woutb + (size_t)i * DMODEL * DI;

        layernorm_k<1><<<L_SEQ, 128, 0, stream>>>(h, ln_w + i * DMODEL, ln_b + i * DMODEL, nullptr, hnb);
        gemm_mfma<128, 0, false, false, true, 1><<<dim3(2 * DI / 128, L_SEQ / 128), 256, 0, stream>>>(
            hnb, DMODEL, inw, DMODEL, nullptr, nullptr, XZb, 2 * DI, DMODEL);
        conv_silu_k<<<L_SEQ * DI / 4 / 256, 256, 0, stream>>>(XZb, cwi, cbi, XCb);
        // B/C slabs (split-K=4)
        gemm_mfma<64, 0, false, false, false, 4><<<dim3(4, L_SEQ / 128), 256, 0, stream>>>(
            XCb, DI, xpw, DI, nullptr, xdblP, nullptr, 64, DI / 4);
        // dt = softplus(XC @ W2.T + dtb), fused GEMM -> bf16 dtg
        gemm_mfma<64, 3, true, false, true, 1><<<dim3(DI / 64, L_SEQ / 128), 256, 0, stream>>>(
            XCb, DI, W2i, DI, dtbv, nullptr, dtgB, DI, DI);
        scanA_k<<<dim3(DI / 256, NCHK), 256, 0, stream>>>(
            XCb, xdblP, dtgB, As2i, dtsumB, sHb);
        scanB1_k<<<dim3(NPAIR / 256, NG), 256, 0, stream>>>(dtsumB, sHb, As2i, PGb, HGb);
        scanB2_k<<<NPAIR / 256, 256, 0, stream>>>(PGb, HGb, GinB);
        scanB3_k<<<dim3(NPAIR / 256, NG), 256, 0, stream>>>(dtsumB, sHb, As2i, GinB, HinB);
        scanC_k<<<dim3(DI / 256, NCHK), 256, 0, stream>>>(
            XCb, xdblP, dtgB, As2i, Dpi, XZb, HinB, yzb);
        gemm_mfma<64, 0, false, true, false, 1><<<dim3(DMODEL / 64, L_SEQ / 128), 256, 0, stream>>>(
            yzb, DI, owi, DI, nullptr, h, nullptr, DMODEL, DI);
    }

    // final LN (f32 + bf16), attention pooling, head
    layernorm_k<2><<<L_SEQ, 128, 0, stream>>>(h, norm_w, norm_b, hn, hnb);
    gemm_mfma<64, 2, true, false, false, 1><<<dim3(2, L_SEQ / 128), 256, 0, stream>>>(
        hnb, DMODEL, w1b, DMODEL, attn_b1, At, nullptr, 128, DMODEL);
    score_k<<<L_SEQ / 256, 256, 0, stream>>>(At, attn_w2, attn_b2, sc);
    softmax_k<<<1, 256, 0, stream>>>(sc, pb);
    pool_partial_k<<<dim3(2, 32), 256, 0, stream>>>(pb, hn, part);
    pool_reduce_k<<<2, 256, 0, stream>>>(part, hp);
    final_head_k<<<1, 256, 0, stream>>>(hp, cls_w, cls_b, label, out);
}

// Round 16
// 393.548 us; speedup vs baseline: 1.1393x; 1.1393x over previous
//
#include <hip/hip_runtime.h>
#include <math.h>

#define L_SEQ 4096
#define DMODEL 512
#define DIN    1024
#define DI     1024
#define DS     16
#define DC     4
#define DTR    32
#define NCHK   512
#define CL     8
#define NPAIR  (DI * DS)          // 16384 (d,s) pairs
#define NG     32                 // groups in chunk-scan
#define GS     16                 // chunks per group (NG*GS == NCHK)
#define SLAB   (L_SEQ * 64)

typedef __bf16 bf16x8 __attribute__((ext_vector_type(8)));
typedef __bf16 bf16x4 __attribute__((ext_vector_type(4)));
typedef float floatx4 __attribute__((ext_vector_type(4)));

#define RLN2 1.44269504f     // log2(e)
#define LN2  0.69314718f

// native softplus: ln(1+e^x) = ln2 * log2(1 + 2^(x*log2e))
__device__ __forceinline__ float softplus_fast(float x) {
    if (x > 20.f) return x;
    float e = __builtin_amdgcn_exp2f(x * RLN2);
    return LN2 * __builtin_amdgcn_logf(1.f + e);   // v_log_f32 = log2
}

__device__ __forceinline__ void gl2lds16(const __bf16* g, __bf16* l) {
    __builtin_amdgcn_global_load_lds(
        (const __attribute__((address_space(1))) void*)g,
        (__attribute__((address_space(3))) void*)l, 16, 0, 0);
}

// ---------------------------------------------------------------------------
// bf16 MFMA GEMM. A: M x lda bf16. W: N x ldw bf16. BM=128, BK=32, 256 thr.
// BN=128: 4 waves 2x2 (64x64 each). BN=64: 4 waves stacked in M (32x64 each).
// KS>1: blockIdx.x = k-slice. ACT: 0 none, 1 relu, 2 tanh.
// ---------------------------------------------------------------------------
template <int BN, int ACT, bool BIAS, bool ADDDEST, bool OUTBF, int KS>
__global__ __launch_bounds__(256) void gemm_mfma(
    const __bf16* __restrict__ A, int lda,
    const __bf16* __restrict__ W, int ldw,
    const float* __restrict__ bias,
    float* __restrict__ C, __bf16* __restrict__ Cb, int ldc, int K)
{
    __shared__ __align__(16) __bf16 sA[128 * 32];
    __shared__ __align__(16) __bf16 sB[BN * 32];
    const int tid = threadIdx.x;
    const int wid = tid >> 6, lane = tid & 63;
    const int m0 = blockIdx.y * 128;
    int n0;
    if (KS > 1) {
        const int ksl = blockIdx.x;
        A += (size_t)ksl * K;
        W += (size_t)ksl * K;
        C += (size_t)ksl * (size_t)gridDim.y * 128 * ldc;
        n0 = 0;
    } else {
        n0 = blockIdx.x * BN;
    }

    constexpr int MR = (BN == 128) ? 4 : 2;
    constexpr int NR = 4;
    const int wrow = (BN == 128) ? (wid >> 1) * 64 : wid * 32;
    const int wcol = (BN == 128) ? (wid & 1) * 64 : 0;

    const int srowA0 = wid * 32 + (lane >> 2);
    const int scol   = (lane & 3) * 8;
    const __bf16* aSrc0 = A + (size_t)(m0 + srowA0) * lda + scol;
    const __bf16* aSrc1 = aSrc0 + 16 * (size_t)lda;
    __bf16* aDst0 = &sA[wid * 1024];
    __bf16* aDst1 = &sA[wid * 1024 + 512];

    const __bf16* bSrc0;
    const __bf16* bSrc1 = nullptr;
    __bf16* bDst0;
    __bf16* bDst1 = nullptr;
    if (BN == 128) {
        bSrc0 = W + (size_t)(n0 + wid * 32 + (lane >> 2)) * ldw + scol;
        bSrc1 = bSrc0 + 16 * (size_t)ldw;
        bDst0 = &sB[wid * 1024];
        bDst1 = &sB[wid * 1024 + 512];
    } else {
        bSrc0 = W + (size_t)(n0 + wid * 16 + (lane >> 2)) * ldw + scol;
        bDst0 = &sB[wid * 512];
    }

    floatx4 acc[MR][NR] = {};
    const int fr = lane & 15;
    const int fk = (lane >> 4) * 8;

    for (int k0 = 0; k0 < K; k0 += 32) {
        __syncthreads();
        gl2lds16(aSrc0 + k0, aDst0);
        gl2lds16(aSrc1 + k0, aDst1);
        gl2lds16(bSrc0 + k0, bDst0);
        if (BN == 128) gl2lds16(bSrc1 + k0, bDst1);
        __syncthreads();
        bf16x8 af[MR], bfv[NR];
#pragma unroll
        for (int i = 0; i < MR; ++i)
            af[i] = *(const bf16x8*)&sA[(wrow + i * 16 + fr) * 32 + fk];
#pragma unroll
        for (int j = 0; j < NR; ++j)
            bfv[j] = *(const bf16x8*)&sB[(wcol + j * 16 + fr) * 32 + fk];
#pragma unroll
        for (int i = 0; i < MR; ++i)
#pragma unroll
            for (int j = 0; j < NR; ++j)
                acc[i][j] = __builtin_amdgcn_mfma_f32_16x16x32_bf16(
                    af[i], bfv[j], acc[i][j], 0, 0, 0);
    }

#pragma unroll
    for (int i = 0; i < MR; ++i)
#pragma unroll
        for (int j = 0; j < NR; ++j) {
            const int n = n0 + wcol + j * 16 + fr;
            float bv = 0.f;
            if (BIAS) bv = bias[n];
#pragma unroll
            for (int r = 0; r < 4; ++r) {
                const int m = m0 + wrow + i * 16 + (lane >> 4) * 4 + r;
                float v = acc[i][j][r] + bv;
                if (ACT == 1) v = fmaxf(v, 0.f);
                else if (ACT == 2) v = tanhf(v);
                const size_t idx = (size_t)m * ldc + n;
                if (OUTBF) {
                    Cb[idx] = (__bf16)v;
                } else {
                    if (ADDDEST) v += C[idx];
                    C[idx] = v;
                }
            }
        }
}

// ---------------------------------------------------------------------------
// weight prep: 5 f32->bf16 conversions (8-elem units) + dtw transpose, 1 launch
__global__ void prep_k(const float* __restrict__ s0, __bf16* __restrict__ d0, int n0,
                       const float* __restrict__ s1, __bf16* __restrict__ d1, int n1,
                       const float* __restrict__ s2, __bf16* __restrict__ d2, int n2,
                       const float* __restrict__ s3, __bf16* __restrict__ d3, int n3,
                       const float* __restrict__ s4, __bf16* __restrict__ d4, int n4,
                       const float* __restrict__ dtw, float* __restrict__ dtwT, int n5)
{
    int i = blockIdx.x * 256 + threadIdx.x;
    int tot = n0 + n1 + n2 + n3 + n4;
    if (i >= tot) {
        int j = i - tot;                      // dtw transpose, element-wise
        if (j < n5) {
            int l = j >> 15, rem = j & 32767, r = rem >> 5, k = rem & 31;
            dtwT[l * 32768 + k * 1024 + r] = dtw[j];
        }
        return;
    }
    const float* s; __bf16* d; int base;
    if (i < n0) { s = s0; d = d0; base = i; }
    else if (i < n0 + n1) { s = s1; d = d1; base = i - n0; }
    else if (i < n0 + n1 + n2) { s = s2; d = d2; base = i - n0 - n1; }
    else if (i < n0 + n1 + n2 + n3) { s = s3; d = d3; base = i - n0 - n1 - n2; }
    else { s = s4; d = d4; base = i - n0 - n1 - n2 - n3; }
    float4 a = ((const float4*)s)[2 * base], b = ((const float4*)s)[2 * base + 1];
    bf16x8 v;
    v[0] = (__bf16)a.x; v[1] = (__bf16)a.y; v[2] = (__bf16)a.z; v[3] = (__bf16)a.w;
    v[4] = (__bf16)b.x; v[5] = (__bf16)b.y; v[6] = (__bf16)b.z; v[7] = (__bf16)b.w;
    *(bf16x8*)&d[8 * base] = v;
}

__global__ void concat_bf_k(const float* __restrict__ a,
                            const float* __restrict__ b,
                            __bf16* __restrict__ o)
{
    int idx = blockIdx.x * 256 + threadIdx.x;
    int m = idx >> 7, c8 = (idx & 127) << 3;
    const float* src = (c8 < 512) ? &a[(m << 9) + c8] : &b[(m << 9) + c8 - 512];
    float4 x = ((const float4*)src)[0], y = ((const float4*)src)[1];
    bf16x8 v;
    v[0] = (__bf16)x.x; v[1] = (__bf16)x.y; v[2] = (__bf16)x.z; v[3] = (__bf16)x.w;
    v[4] = (__bf16)y.x; v[5] = (__bf16)y.y; v[6] = (__bf16)y.z; v[7] = (__bf16)y.w;
    *(bf16x8*)&o[idx << 3] = v;
}

// LayerNorm over D=512. OMODE: 0 f32, 1 bf16, 2 both.
template <int OMODE>
__global__ __launch_bounds__(128) void layernorm_k(
    const float* __restrict__ X, const float* __restrict__ w,
    const float* __restrict__ b, float* __restrict__ Yf, __bf16* __restrict__ Yb)
{
    const int r = blockIdx.x, tid = threadIdx.x;
    const size_t base = ((size_t)r << 9) + (tid << 2);
    const float4 v = *(const float4*)&X[base];
    float s = v.x + v.y + v.z + v.w;
#pragma unroll
    for (int o = 32; o; o >>= 1) s += __shfl_down(s, o, 64);
    __shared__ float red[2];
    if ((tid & 63) == 0) red[tid >> 6] = s;
    __syncthreads();
    const float mean = (red[0] + red[1]) * (1.f / 512.f);
    float dx = v.x - mean, dy = v.y - mean, dz = v.z - mean, dw = v.w - mean;
    float q = dx * dx + dy * dy + dz * dz + dw * dw;
#pragma unroll
    for (int o = 32; o; o >>= 1) q += __shfl_down(q, o, 64);
    __shared__ float red2[2];
    if ((tid & 63) == 0) red2[tid >> 6] = q;
    __syncthreads();
    const float rs = rsqrtf((red2[0] + red2[1]) * (1.f / 512.f) + 1e-5f);
    const float4 wv = *(const float4*)&w[tid << 2];
    const float4 bv = *(const float4*)&b[tid << 2];
    float o0 = dx * rs * wv.x + bv.x;
    float o1 = dy * rs * wv.y + bv.y;
    float o2 = dz * rs * wv.z + bv.z;
    float o3 = dw * rs * wv.w + bv.w;
    if (OMODE != 1) {
        float4 ov; ov.x = o0; ov.y = o1; ov.z = o2; ov.w = o3;
        *(float4*)&Yf[base] = ov;
    }
    if (OMODE != 0) {
        bf16x4 ov; ov[0] = (__bf16)o0; ov[1] = (__bf16)o1;
        ov[2] = (__bf16)o2; ov[3] = (__bf16)o3;
        *(bf16x4*)&Yb[base] = ov;
    }
}

// depthwise causal conv (DC=4) + SiLU. 4 channels x 1 timestep per thread.
__global__ void conv_silu_k(const __bf16* __restrict__ XZb,
                            const float* __restrict__ cw,
                            const float* __restrict__ cb,
                            __bf16* __restrict__ XCb)
{
    int i = blockIdx.x * 256 + threadIdx.x;
    int t = i >> 8, d4 = (i & 255) << 2;
    float wt[4][4];
#pragma unroll
    for (int d = 0; d < 4; ++d) {
        float4 w = *(const float4*)&cw[(d4 + d) << 2];
        wt[d][0] = w.x; wt[d][1] = w.y; wt[d][2] = w.z; wt[d][3] = w.w;
    }
    float4 c = *(const float4*)&cb[d4];
    float a0 = c.x, a1 = c.y, a2 = c.z, a3 = c.w;
#pragma unroll
    for (int k = 0; k < 4; ++k) {
        int ts = t + k - 3;
        if (ts >= 0) {
            bf16x4 x = *(const bf16x4*)&XZb[((size_t)ts << 11) + d4];
            a0 = fmaf((float)x[0], wt[0][k], a0);
            a1 = fmaf((float)x[1], wt[1][k], a1);
            a2 = fmaf((float)x[2], wt[2][k], a2);
            a3 = fmaf((float)x[3], wt[3][k], a3);
        }
    }
    a0 *= 1.f / (1.f + __expf(-a0));
    a1 *= 1.f / (1.f + __expf(-a1));
    a2 *= 1.f / (1.f + __expf(-a2));
    a3 *= 1.f / (1.f + __expf(-a3));
    bf16x4 ob; ob[0] = (__bf16)a0; ob[1] = (__bf16)a1;
    ob[2] = (__bf16)a2; ob[3] = (__bf16)a3;
    *(bf16x4*)&XCb[((size_t)t << 10) + d4] = ob;
}

// ---------------------------------------------------------------------------
// Selective scan, chunked (CL=8, NCHK=512 -> 2048 blocks).
// ---------------------------------------------------------------------------
__global__ __launch_bounds__(256) void scanA_k(
    const __bf16* __restrict__ xc, const float* __restrict__ xdblP,
    const float* __restrict__ dtwT, const float* __restrict__ dtb,
    const float* __restrict__ Alog,
    __bf16* __restrict__ sP, __bf16* __restrict__ sH,
    __bf16* __restrict__ dtg)
{
    const int d = blockIdx.x * 256 + threadIdx.x;
    const int c = blockIdx.y;
    const int tid = threadIdx.x;
    __shared__ float xlow[CL][DTR];          // 8x32
    __shared__ float Bs[CL][DS];             // 8x16
    __shared__ float dts[CL][256];           // 8 KB
    {
        int t = tid >> 5, k = tid & 31;      // CL*DTR == 256
        size_t g = (size_t)(c * CL + t) * 64 + k;
        xlow[t][k] = xdblP[g] + xdblP[SLAB + g] + xdblP[2 * SLAB + g] + xdblP[3 * SLAB + g];
    }
    if (tid < CL * DS) {
        int t = tid >> 4, s = tid & 15;
        size_t g = (size_t)(c * CL + t) * 64 + 32 + s;
        Bs[t][s] = xdblP[g] + xdblP[SLAB + g] + xdblP[2 * SLAB + g] + xdblP[3 * SLAB + g];
    }
    __syncthreads();
    // phase 1: parallel dt dots (independent across t)
    float dtw_d[32];
#pragma unroll
    for (int k = 0; k < 32; ++k) dtw_d[k] = dtwT[k * 1024 + d];
    const float dtb_d = dtb[d];
    float sumdt = 0.f;
#pragma unroll
    for (int t = 0; t < CL; ++t) {
        float p0 = 0.f, p1 = 0.f, p2 = 0.f, p3 = 0.f;
#pragma unroll
        for (int k4 = 0; k4 < 8; ++k4) {
            float4 xq = *(const float4*)&xlow[t][k4 * 4];
            p0 = fmaf(xq.x, dtw_d[k4 * 4 + 0], p0);
            p1 = fmaf(xq.y, dtw_d[k4 * 4 + 1], p1);
            p2 = fmaf(xq.z, dtw_d[k4 * 4 + 2], p2);
            p3 = fmaf(xq.w, dtw_d[k4 * 4 + 3], p3);
        }
        float acc = ((p0 + p1) + (p2 + p3)) + dtb_d;
        float dtv = softplus_fast(acc);
        dts[t][tid] = dtv;
        dtg[((size_t)(c * CL + t) << 10) + d] = (__bf16)dtv;
        sumdt += dtv;
    }
    // phase 2: serial scan
    float As2[DS], h[DS];
    {
        const float4* Ap4 = (const float4*)&Alog[(size_t)d * DS];
#pragma unroll
        for (int q = 0; q < 4; ++q) {
            float4 a = Ap4[q];
            As2[q * 4 + 0] = -__expf(a.x) * RLN2; As2[q * 4 + 1] = -__expf(a.y) * RLN2;
            As2[q * 4 + 2] = -__expf(a.z) * RLN2; As2[q * 4 + 3] = -__expf(a.w) * RLN2;
        }
    }
#pragma unroll
    for (int s = 0; s < DS; ++s) h[s] = 0.f;
    for (int t = 0; t < CL; ++t) {
        float dtv = dts[t][tid];
        float xv = (float)xc[((size_t)(c * CL + t) << 10) + d];
        float dx = dtv * xv;
        float barr[16];
#pragma unroll
        for (int q = 0; q < 4; ++q) {
            float4 b = *(const float4*)&Bs[t][q * 4];
            barr[q * 4 + 0] = b.x; barr[q * 4 + 1] = b.y;
            barr[q * 4 + 2] = b.z; barr[q * 4 + 3] = b.w;
        }
#pragma unroll
        for (int s = 0; s < DS; ++s) {
            float a = exp2f(dtv * As2[s]);
            h[s] = fmaf(a, h[s], dx * barr[s]);
        }
    }
    size_t base = ((size_t)c * DI + d) * DS;
    bf16x8 p0v, p1v, h0v, h1v;
#pragma unroll
    for (int s = 0; s < 8; ++s) {
        p0v[s] = (__bf16)exp2f(As2[s] * sumdt);
        p1v[s] = (__bf16)exp2f(As2[s + 8] * sumdt);
        h0v[s] = (__bf16)h[s];
        h1v[s] = (__bf16)h[s + 8];
    }
    *(bf16x8*)&sP[base] = p0v; *(bf16x8*)&sP[base + 8] = p1v;
    *(bf16x8*)&sH[base] = h0v; *(bf16x8*)&sH[base + 8] = h1v;
}

// ---------------------------------------------------------------------------
// Hierarchical chunk-scan. Pair index p in [0,16384); sP/sH layout [c][p].
// B1: per-(p, group): fold GS chunks -> (PG,HG). B2: scan NG group summaries
// per pair -> Gin. B3: replay within group writing Hin[c][p].
// ---------------------------------------------------------------------------
__global__ __launch_bounds__(256) void scanB1_k(
    const __bf16* __restrict__ sP, const __bf16* __restrict__ sH,
    __bf16* __restrict__ PG, __bf16* __restrict__ HG)
{
    int p = blockIdx.x * 256 + threadIdx.x;
    int g = blockIdx.y;
    float rp = 1.f, rh = 0.f;
#pragma unroll
    for (int k = 0; k < GS; ++k) {
        size_t idx = (size_t)(g * GS + k) * NPAIR + p;
        float P = (float)sP[idx], H = (float)sH[idx];
        rh = fmaf(P, rh, H);
        rp *= P;
    }
    PG[(size_t)g * NPAIR + p] = (__bf16)rp;
    HG[(size_t)g * NPAIR + p] = (__bf16)rh;
}

__global__ __launch_bounds__(256) void scanB2_k(
    const __bf16* __restrict__ PG, const __bf16* __restrict__ HG,
    __bf16* __restrict__ Gin)
{
    int p = blockIdx.x * 256 + threadIdx.x;
    float run = 0.f;
#pragma unroll
    for (int g = 0; g < NG; ++g) {
        size_t idx = (size_t)g * NPAIR + p;
        Gin[idx] = (__bf16)run;
        run = fmaf((float)PG[idx], run, (float)HG[idx]);
    }
}

__global__ __launch_bounds__(256) void scanB3_k(
    const __bf16* __restrict__ sP, const __bf16* __restrict__ sH,
    const __bf16* __restrict__ Gin, __bf16* __restrict__ Hin)
{
    int p = blockIdx.x * 256 + threadIdx.x;
    int g = blockIdx.y;
    float run = (float)Gin[(size_t)g * NPAIR + p];
#pragma unroll
    for (int k = 0; k < GS; ++k) {
        size_t idx = (size_t)(g * GS + k) * NPAIR + p;
        Hin[idx] = (__bf16)run;
        run = fmaf((float)sP[idx], run, (float)sH[idx]);
    }
}

__global__ __launch_bounds__(256) void scanC_k(
    const __bf16* __restrict__ xc, const float* __restrict__ xdblP,
    const __bf16* __restrict__ dtg,
    const float* __restrict__ Alog, const float* __restrict__ Dp,
    const __bf16* __restrict__ XZb, const __bf16* __restrict__ Hin,
    __bf16* __restrict__ yz)
{
    const int d = blockIdx.x * 256 + threadIdx.x;
    const int c = blockIdx.y;
    const int tid = threadIdx.x;
    __shared__ float Bs[CL][DS], Cs[CL][DS];
    if (tid < CL * DS) {
        int t = tid >> 4, s = tid & 15;
        size_t g = (size_t)(c * CL + t) * 64 + 32 + s;
        Bs[t][s] = xdblP[g] + xdblP[SLAB + g] + xdblP[2 * SLAB + g] + xdblP[3 * SLAB + g];
        g += 16;
        Cs[t][s] = xdblP[g] + xdblP[SLAB + g] + xdblP[2 * SLAB + g] + xdblP[3 * SLAB + g];
    }
    __syncthreads();
    float As2[DS], h[DS];
    {
        const float4* Ap4 = (const float4*)&Alog[(size_t)d * DS];
#pragma unroll
        for (int q = 0; q < 4; ++q) {
            float4 a = Ap4[q];
            As2[q * 4 + 0] = -__expf(a.x) * RLN2; As2[q * 4 + 1] = -__expf(a.y) * RLN2;
            As2[q * 4 + 2] = -__expf(a.z) * RLN2; As2[q * 4 + 3] = -__expf(a.w) * RLN2;
        }
    }
    {
        size_t base = ((size_t)c * DI + d) * DS;
        bf16x8 h0 = *(const bf16x8*)&Hin[base];
        bf16x8 h1 = *(const bf16x8*)&Hin[base + 8];
#pragma unroll
        for (int s = 0; s < 8; ++s) { h[s] = (float)h0[s]; h[s + 8] = (float)h1[s]; }
    }
    const float Dd = Dp[d];
    for (int t = 0; t < CL; ++t) {
        size_t tg = (size_t)(c * CL + t);
        const float dtv = (float)dtg[(tg << 10) + d];
        const float xv = (float)xc[(tg << 10) + d];
        const float dx = dtv * xv;
        float barr[16], carr[16];
#pragma unroll
        for (int q = 0; q < 4; ++q) {
            float4 b = *(const float4*)&Bs[t][q * 4];
            float4 cc = *(const float4*)&Cs[t][q * 4];
            barr[q * 4 + 0] = b.x; barr[q * 4 + 1] = b.y;
            barr[q * 4 + 2] = b.z; barr[q * 4 + 3] = b.w;
            carr[q * 4 + 0] = cc.x; carr[q * 4 + 1] = cc.y;
            carr[q * 4 + 2] = cc.z; carr[q * 4 + 3] = cc.w;
        }
        float y = 0.f;
#pragma unroll
        for (int s = 0; s < DS; ++s) {
            float a = exp2f(dtv * As2[s]);
            h[s] = fmaf(a, h[s], dx * barr[s]);
            y = fmaf(h[s], carr[s], y);
        }
        y = fmaf(Dd, xv, y);
        float zv = (float)XZb[(tg << 11) + 1024 + d];
        float sg = 1.f / (1.f + __expf(-zv));
        yz[(tg << 10) + d] = (__bf16)(y * (zv * sg));
    }
}

// ---------------------------------------------------------------------------
// Attention pooling tail
// ---------------------------------------------------------------------------
__global__ void score_k(const float* __restrict__ At,
                        const float* __restrict__ w2,
                        const float* __restrict__ b2,
                        float* __restrict__ sc)
{
    int t = blockIdx.x * 256 + threadIdx.x;
    const float4* a = (const float4*)(At + ((size_t)t << 7));
    const float4* w = (const float4*)w2;
    float acc = 0.f;
#pragma unroll
    for (int j = 0; j < 32; ++j) {
        float4 av = a[j], wv = w[j];
        acc += av.x * wv.x + av.y * wv.y + av.z * wv.z + av.w * wv.w;
    }
    sc[t] = acc + b2[0];
}

__global__ __launch_bounds__(256) void softmax_k(const float* __restrict__ s,
                                                 float* __restrict__ p)
{
    const int tid = threadIdx.x;
    float vals[16];
#pragma unroll
    for (int i = 0; i < 4; ++i) {
        float4 v = *(const float4*)&s[(tid << 4) + (i << 2)];
        vals[i * 4 + 0] = v.x; vals[i * 4 + 1] = v.y;
        vals[i * 4 + 2] = v.z; vals[i * 4 + 3] = v.w;
    }
    float mx = -1e30f;
#pragma unroll
    for (int i = 0; i < 16; ++i) mx = fmaxf(mx, vals[i]);
#pragma unroll
    for (int o = 32; o; o >>= 1) mx = fmaxf(mx, __shfl_xor(mx, o, 64));
    __shared__ float red[4];
    if ((tid & 63) == 0) red[tid >> 6] = mx;
    __syncthreads();
    mx = fmaxf(fmaxf(red[0], red[1]), fmaxf(red[2], red[3]));
    float sum = 0.f, e[16];
#pragma unroll
    for (int i = 0; i < 16; ++i) { e[i] = __expf(vals[i] - mx); sum += e[i]; }
#pragma unroll
    for (int o = 32; o; o >>= 1) sum += __shfl_xor(sum, o, 64);
    __syncthreads();
    if ((tid & 63) == 0) red[tid >> 6] = sum;
    __syncthreads();
    sum = red[0] + red[1] + red[2] + red[3];
    float inv = 1.f / sum;
#pragma unroll
    for (int i = 0; i < 4; ++i) {
        float4 ov;
        ov.x = e[i * 4 + 0] * inv; ov.y = e[i * 4 + 1] * inv;
        ov.z = e[i * 4 + 2] * inv; ov.w = e[i * 4 + 3] * inv;
        *(float4*)&p[(tid << 4) + (i << 2)] = ov;
    }
}

__global__ void pool_partial_k(const float* __restrict__ prob,
                               const float* __restrict__ hln,
                               float* __restrict__ part)
{
    int j = blockIdx.x * 256 + threadIdx.x;
    int c = blockIdx.y;
    float acc = 0.f;
    for (int t = c * 128; t < (c + 1) * 128; ++t)
        acc = fmaf(prob[t], hln[((size_t)t << 9) + j], acc);
    part[c * 512 + j] = acc;
}

__global__ void pool_reduce_k(const float* __restrict__ part,
                              float* __restrict__ hp)
{
    int j = blockIdx.x * 256 + threadIdx.x;
    float acc = 0.f;
    for (int c = 0; c < 32; ++c) acc += part[c * 512 + j];
    hp[j] = acc;
}

__global__ __launch_bounds__(256) void final_head_k(
    const float* __restrict__ hp, const float* __restrict__ cls_w,
    const float* __restrict__ cls_b, const int* __restrict__ label,
    float* __restrict__ out)
{
    const int w = threadIdx.x >> 6, lane = threadIdx.x & 63;
    float acc = 0.f;
    for (int k = lane; k < 512; k += 64) acc += hp[k] * cls_w[w * 512 + k];
#pragma unroll
    for (int o = 32; o; o >>= 1) acc += __shfl_down(acc, o, 64);
    __shared__ float lg[4];
    if (lane == 0) lg[w] = acc + cls_b[w];
    __syncthreads();
    if (threadIdx.x == 0) {
        float lce[4];
        for (int c = 0; c < 4; ++c) {
            float z = lg[c];
            float hz = 1.f / (1.f + expf(-z));
            float pc = fminf(fmaxf(hz, 1e-6f), 1.f - 1e-6f);
            lce[c] = logf(pc) - log1pf(-pc);
        }
        float mx = fmaxf(fmaxf(lce[0], lce[1]), fmaxf(lce[2], lce[3]));
        float se = 0.f;
        for (int c = 0; c < 4; ++c) se += expf(lce[c] - mx);
        for (int c = 0; c < 4; ++c) out[c] = lce[c];
        for (int c = 0; c < 4; ++c) out[4 + c] = expf(lce[c] - mx) / se;
        int lb = label[0];
        out[8] = -(lce[lb] - mx - logf(se));
    }
}

// ---------------------------------------------------------------------------
extern "C" void kernel_launch(void* const* d_in, const int* in_sizes, int n_in,
                              void* d_out, int out_size, void* d_ws, size_t ws_size,
                              hipStream_t stream)
{
    const float* data_s   = (const float*)d_in[0];
    const float* data_l   = (const float*)d_in[1];
    const int*   label    = (const int*)d_in[3];
    const float* fc1_w    = (const float*)d_in[4];
    const float* fc1_b    = (const float*)d_in[5];
    const float* ln_w     = (const float*)d_in[6];
    const float* ln_b     = (const float*)d_in[7];
    const float* in_proj_w= (const float*)d_in[8];
    const float* conv_w   = (const float*)d_in[9];
    const float* conv_b   = (const float*)d_in[10];
    const float* x_proj_w = (const float*)d_in[11];
    const float* dt_proj_w= (const float*)d_in[12];
    const float* dt_proj_b= (const float*)d_in[13];
    const float* A_log    = (const float*)d_in[14];
    const float* D_param  = (const float*)d_in[15];
    const float* out_proj_w=(const float*)d_in[16];
    const float* norm_w   = (const float*)d_in[17];
    const float* norm_b   = (const float*)d_in[18];
    const float* attn_w1  = (const float*)d_in[19];
    const float* attn_b1  = (const float*)d_in[20];
    const float* attn_w2  = (const float*)d_in[21];
    const float* attn_b2  = (const float*)d_in[22];
    const float* cls_w    = (const float*)d_in[23];
    const float* cls_b    = (const float*)d_in[24];
    float* out = (float*)d_out;

    // ---- f32 workspace ----
    float* ws = (float*)d_ws;
    size_t off = 0;
    float* h     = ws + off; off += (size_t)L_SEQ * DMODEL;
    float* hn    = ws + off; off += (size_t)L_SEQ * DMODEL;
    float* xdblP = ws + off; off += (size_t)4 * SLAB;
    float* dtwT  = ws + off; off += (size_t)2 * DTR * DI;
    float* At    = ws + off; off += (size_t)L_SEQ * 128;
    float* sc    = ws + off; off += L_SEQ;
    float* pb    = ws + off; off += L_SEQ;
    float* part  = ws + off; off += 32 * 512;
    float* hp    = ws + off; off += 512;

    // ---- bf16 workspace ----
    __bf16* bws = (__bf16*)(ws + off);
    size_t boff = 0;
    __bf16* Acatb = bws + boff; boff += (size_t)L_SEQ * DIN;
    __bf16* hnb   = bws + boff; boff += (size_t)L_SEQ * DMODEL;
    __bf16* XZb   = bws + boff; boff += (size_t)L_SEQ * 2 * DI;
    __bf16* XCb   = bws + boff; boff += (size_t)L_SEQ * DI;
    __bf16* yzb   = bws + boff; boff += (size_t)L_SEQ * DI;
    __bf16* sPb   = bws + boff; boff += (size_t)NCHK * NPAIR;
    __bf16* sHb   = bws + boff; boff += (size_t)NCHK * NPAIR;
    __bf16* HinB  = bws + boff; boff += (size_t)NCHK * NPAIR;
    __bf16* dtgB  = bws + boff; boff += (size_t)L_SEQ * DI;
    __bf16* PGb   = bws + boff; boff += (size_t)NG * NPAIR;
    __bf16* HGb   = bws + boff; boff += (size_t)NG * NPAIR;
    __bf16* GinB  = bws + boff; boff += (size_t)NG * NPAIR;
    __bf16* wfc1b = bws + boff; boff += (size_t)DMODEL * DIN;
    __bf16* winb  = bws + boff; boff += (size_t)2 * 2 * DI * DMODEL;
    __bf16* wxpb  = bws + boff; boff += (size_t)2 * 64 * DI;
    __bf16* woutb = bws + boff; boff += (size_t)2 * DMODEL * DI;
    __bf16* w1b   = bws + boff; boff += (size_t)128 * DMODEL;
    if (ws_size < off * sizeof(float) + boff * sizeof(__bf16)) return;

    // ---- weight prep (single launch: 5 converts + dtw transpose) ----
    const int n0 = DMODEL * DIN / 8;
    const int n1 = 2 * 2 * DI * DMODEL / 8;
    const int n2 = 2 * 64 * DI / 8;
    const int n3 = 2 * DMODEL * DI / 8;
    const int n4 = 128 * DMODEL / 8;
    const int n5 = 2 * DI * DTR;
    prep_k<<<(n0 + n1 + n2 + n3 + n4 + n5 + 255) / 256, 256, 0, stream>>>(
        fc1_w, wfc1b, n0, in_proj_w, winb, n1, x_proj_w, wxpb, n2,
        out_proj_w, woutb, n3, attn_w1, w1b, n4, dt_proj_w, dtwT, n5);

    // h = relu(concat @ fc1_w.T + b)
    concat_bf_k<<<L_SEQ * DIN / 8 / 256, 256, 0, stream>>>(data_s, data_l, Acatb);
    gemm_mfma<64, 1, true, false, false, 1><<<dim3(DMODEL / 64, L_SEQ / 128), 256, 0, stream>>>(
        Acatb, DIN, wfc1b, DIN, fc1_b, h, nullptr, DMODEL, DIN);

    for (int i = 0; i < 2; ++i) {
        const __bf16* inw = winb + (size_t)i * 2 * DI * DMODEL;
        const float* cwi = conv_w + (size_t)i * DI * DC;
        const float* cbi = conv_b + (size_t)i * DI;
        const __bf16* xpw = wxpb + (size_t)i * 64 * DI;
        const float* dtwTi = dtwT + (size_t)i * DTR * DI;
        const float* dtbv= dt_proj_b + (size_t)i * DI;
        const float* Alg = A_log + (size_t)i * DI * DS;
        const float* Dpi = D_param + (size_t)i * DI;
        const __bf16* owi = woutb + (size_t)i * DMODEL * DI;

        layernorm_k<1><<<L_SEQ, 128, 0, stream>>>(h, ln_w + i * DMODEL, ln_b + i * DMODEL, nullptr, hnb);
        gemm_mfma<128, 0, false, false, true, 1><<<dim3(2 * DI / 128, L_SEQ / 128), 256, 0, stream>>>(
            hnb, DMODEL, inw, DMODEL, nullptr, nullptr, XZb, 2 * DI, DMODEL);
        conv_silu_k<<<L_SEQ * DI / 4 / 256, 256, 0, stream>>>(XZb, cwi, cbi, XCb);
        gemm_mfma<64, 0, false, false, false, 4><<<dim3(4, L_SEQ / 128), 256, 0, stream>>>(
            XCb, DI, xpw, DI, nullptr, xdblP, nullptr, 64, DI / 4);
        scanA_k<<<dim3(DI / 256, NCHK), 256, 0, stream>>>(XCb, xdblP, dtwTi, dtbv, Alg, sPb, sHb, dtgB);
        scanB1_k<<<dim3(NPAIR / 256, NG), 256, 0, stream>>>(sPb, sHb, PGb, HGb);
        scanB2_k<<<NPAIR / 256, 256, 0, stream>>>(PGb, HGb, GinB);
        scanB3_k<<<dim3(NPAIR / 256, NG), 256, 0, stream>>>(sPb, sHb, GinB, HinB);
        scanC_k<<<dim3(DI / 256, NCHK), 256, 0, stream>>>(XCb, xdblP, dtgB, Alg, Dpi, XZb, HinB, yzb);
        gemm_mfma<64, 0, false, true, false, 1><<<dim3(DMODEL / 64, L_SEQ / 128), 256, 0, stream>>>(
            yzb, DI, owi, DI, nullptr, h, nullptr, DMODEL, DI);
    }

    // final LN (f32 + bf16), attention pooling, head
    layernorm_k<2><<<L_SEQ, 128, 0, stream>>>(h, norm_w, norm_b, hn, hnb);
    gemm_mfma<64, 2, true, false, false, 1><<<dim3(2, L_SEQ / 128), 256, 0, stream>>>(
        hnb, DMODEL, w1b, DMODEL, attn_b1, At, nullptr, 128, DMODEL);
    score_k<<<L_SEQ / 256, 256, 0, stream>>>(At, attn_w2, attn_b2, sc);
    softmax_k<<<1, 256, 0, stream>>>(sc, pb);
    pool_partial_k<<<dim3(2, 32), 256, 0, stream>>>(pb, hn, part);
    pool_reduce_k<<<2, 256, 0, stream>>>(part, hp);
    final_head_k<<<1, 256, 0, stream>>>(hp, cls_w, cls_b, label, out);
}